// Round 1
// baseline (257.697 us; speedup 1.0000x reference)
//
#include <hip/hip_runtime.h>
#include <math.h>

constexpr int kB  = 4;
constexpr int kN  = 512;
constexpr int kE  = 512;
constexpr int kH  = 8;
constexpr int kH2 = 16;
constexpr int kC  = 64;
constexpr int kDV = 64;
constexpr float kLamInit = 0.2f;

// ---------------------------------------------------------------- K0: lambda
__global__ void lam_kernel(const float* __restrict__ lq1, const float* __restrict__ lk1,
                           const float* __restrict__ lq2, const float* __restrict__ lk2,
                           float* __restrict__ lam_out) {
  int lane = threadIdx.x;  // 64 threads
  float s1 = 0.f, s2 = 0.f;
  for (int i = lane; i < kE; i += 64) { s1 += lq1[i] * lk1[i]; s2 += lq2[i] * lk2[i]; }
  #pragma unroll
  for (int off = 32; off; off >>= 1) { s1 += __shfl_xor(s1, off); s2 += __shfl_xor(s2, off); }
  if (lane == 0) lam_out[0] = expf(s1) - expf(s2) + kLamInit;
}

// ------------------------------------------------- K1/K4: C[M,N] = A[M,K] * B[N,K]^T
__global__ __launch_bounds__(256) void sgemm_abt(const float* __restrict__ A,
                                                 const float* __restrict__ B,
                                                 float* __restrict__ C,
                                                 int M, int N, int K) {
  __shared__ float As[16][68];  // [k][m], stride 68 -> 16B-aligned rows, conflict-free
  __shared__ float Bs[16][68];
  const int tid = threadIdx.x;
  const int tx = tid & 15, ty = tid >> 4;
  const int m0 = blockIdx.y * 64, f0 = blockIdx.x * 64;
  const int lr = tid >> 2, lc = tid & 3;
  float acc[4][4] = {};
  const float* Ap = A + (size_t)(m0 + lr) * K + lc * 4;
  const float* Bp = B + (size_t)(f0 + lr) * K + lc * 4;
  for (int k0 = 0; k0 < K; k0 += 16) {
    const float4 av = *(const float4*)(Ap + k0);
    const float4 bv = *(const float4*)(Bp + k0);
    __syncthreads();
    As[lc*4+0][lr]=av.x; As[lc*4+1][lr]=av.y; As[lc*4+2][lr]=av.z; As[lc*4+3][lr]=av.w;
    Bs[lc*4+0][lr]=bv.x; Bs[lc*4+1][lr]=bv.y; Bs[lc*4+2][lr]=bv.z; Bs[lc*4+3][lr]=bv.w;
    __syncthreads();
    #pragma unroll
    for (int k = 0; k < 16; ++k) {
      const float4 a = *(const float4*)&As[k][ty*4];
      const float4 b = *(const float4*)&Bs[k][tx*4];
      acc[0][0]+=a.x*b.x; acc[0][1]+=a.x*b.y; acc[0][2]+=a.x*b.z; acc[0][3]+=a.x*b.w;
      acc[1][0]+=a.y*b.x; acc[1][1]+=a.y*b.y; acc[1][2]+=a.y*b.z; acc[1][3]+=a.y*b.w;
      acc[2][0]+=a.z*b.x; acc[2][1]+=a.z*b.y; acc[2][2]+=a.z*b.z; acc[2][3]+=a.z*b.w;
      acc[3][0]+=a.w*b.x; acc[3][1]+=a.w*b.y; acc[3][2]+=a.w*b.z; acc[3][3]+=a.w*b.w;
    }
  }
  #pragma unroll
  for (int i = 0; i < 4; ++i) {
    float4 o = make_float4(acc[i][0], acc[i][1], acc[i][2], acc[i][3]);
    *(float4*)(C + (size_t)(m0 + ty*4 + i) * N + f0 + tx*4) = o;
  }
}

// -------------------- K2: ue = u @ uproj_w^T + b, mask -> -1e30, write ue_t[b,h2,q,k]
// block: (mt: 32 q's, nt: 16 k's, b). u is read in natural (coalesced) order; output
// transposed through LDS so global writes are 64B-contiguous segments.
__global__ __launch_bounds__(256) void ue_kernel(const float* __restrict__ u,
                                                 const int* __restrict__ umask,
                                                 const float* __restrict__ uw,
                                                 const float* __restrict__ ub,
                                                 float* __restrict__ ue_t) {
  __shared__ float u_lds[32 * 68];     // [m][c], stride 68
  __shared__ float out_lds[16 * 545];  // [h2] plane stride 545 = 32*17+1; [m]*17+[n]
  const int tid = threadIdx.x;
  const int h2 = tid & 15, mi = tid >> 4;  // mi in 0..15
  const int mt = blockIdx.x, nt = blockIdx.y, b = blockIdx.z;
  float wreg[64];
  #pragma unroll
  for (int c4 = 0; c4 < 16; ++c4) {
    const float4 wv = *(const float4*)(uw + h2 * 64 + c4 * 4);
    wreg[c4*4+0]=wv.x; wreg[c4*4+1]=wv.y; wreg[c4*4+2]=wv.z; wreg[c4*4+3]=wv.w;
  }
  const float bias = ub[h2];
  for (int nl = 0; nl < 16; ++nl) {
    const int n = nt * 16 + nl;  // key index k
    const float* usrc = u + (((size_t)b * kN + n) * kN + mt * 32) * kC;
    __syncthreads();  // previous iteration's u_lds reads complete
    {
      const int i0 = tid * 4;
      *(float4*)&u_lds[(i0 >> 6) * 68 + (i0 & 63)] = *(const float4*)(usrc + i0);
      const int i1 = (tid + 256) * 4;
      *(float4*)&u_lds[(i1 >> 6) * 68 + (i1 & 63)] = *(const float4*)(usrc + i1);
    }
    __syncthreads();
    #pragma unroll
    for (int rep = 0; rep < 2; ++rep) {
      const int mloc = mi + 16 * rep;
      float acc = bias;
      #pragma unroll
      for (int c4 = 0; c4 < 16; ++c4) {
        const float4 uv = *(const float4*)&u_lds[mloc*68 + c4*4];
        acc += uv.x*wreg[c4*4] + uv.y*wreg[c4*4+1] + uv.z*wreg[c4*4+2] + uv.w*wreg[c4*4+3];
      }
      const int msk = umask[(((size_t)b * kN + n) * kN + mt*32 + mloc) * kH2 + h2];
      out_lds[h2*545 + mloc*17 + nl] = msk ? -1e30f : acc;
    }
  }
  __syncthreads();
  for (int idx = tid; idx < 16*32*16; idx += 256) {
    const int nl = idx & 15, mloc = (idx >> 4) & 31, ho = idx >> 9;
    ue_t[(((size_t)b*kH2 + ho)*kN + mt*32 + mloc)*kN + nt*16 + nl] =
        out_lds[ho*545 + mloc*17 + nl];
  }
}

// ---------- K3: softmax (over k) + diff + PV + LayerNorm, per (b, h, 32-q tile)
__global__ __launch_bounds__(256) void attn_kernel(const float* __restrict__ ue_t,
                                                   const float* __restrict__ v_full,
                                                   const float* __restrict__ lam_p,
                                                   const float* __restrict__ ln_w,
                                                   const float* __restrict__ ln_b,
                                                   float* __restrict__ attn_flat) {
  __shared__ float p_lds[32 * 33];   // [q][k-tile], stride 33
  __shared__ float v_lds[32 * 68];   // [k][d], stride 68
  __shared__ float m_sh[2][32];
  __shared__ float il_sh[2][32];
  const int tid = threadIdx.x;
  const int qt = blockIdx.x, h = blockIdx.y, b = blockIdx.z;
  const int q0 = qt * 32;
  const float lam = lam_p[0];
  const float* base0 = ue_t + ((size_t)(b*kH2 + 2*h) * kN) * kN;

  // phase 1: per-row max & sum(exp) for s=0,1 rows (64 rows of 512, one wave per row)
  const int wave = tid >> 6, lane = tid & 63;
  for (int i = 0; i < 16; ++i) {
    const int r = wave * 16 + i;
    const int s = r >> 5, qloc = r & 31;
    const float* row = base0 + ((size_t)s*kN + q0 + qloc) * kN;
    const float4 a = *(const float4*)(row + lane*8);
    const float4 c = *(const float4*)(row + lane*8 + 4);
    float rm = fmaxf(fmaxf(fmaxf(a.x,a.y),fmaxf(a.z,a.w)),
                     fmaxf(fmaxf(c.x,c.y),fmaxf(c.z,c.w)));
    #pragma unroll
    for (int off = 32; off; off >>= 1) rm = fmaxf(rm, __shfl_xor(rm, off));
    float e = __expf(a.x-rm)+__expf(a.y-rm)+__expf(a.z-rm)+__expf(a.w-rm)
            + __expf(c.x-rm)+__expf(c.y-rm)+__expf(c.z-rm)+__expf(c.w-rm);
    #pragma unroll
    for (int off = 32; off; off >>= 1) e += __shfl_xor(e, off);
    if (lane == 0) { m_sh[s][qloc] = rm; il_sh[s][qloc] = 1.0f / e; }
  }
  __syncthreads();

  // phase 2: PV over k tiles of 32
  float acc[8] = {};
  const int q = tid >> 3, dg = tid & 7;
  for (int k0 = 0; k0 < kN; k0 += 32) {
    __syncthreads();
    #pragma unroll
    for (int j = 0; j < 4; ++j) {
      const int idx = tid + 256*j;
      const int kk = idx & 31, qq = idx >> 5;
      const float* r0 = base0 + (size_t)(q0 + qq) * kN;
      const float e0 = r0[k0 + kk];
      const float e1 = r0[(size_t)kN*kN + k0 + kk];
      p_lds[qq*33 + kk] = __expf(e0 - m_sh[0][qq]) * il_sh[0][qq]
                        - lam * __expf(e1 - m_sh[1][qq]) * il_sh[1][qq];
    }
    #pragma unroll
    for (int j = 0; j < 2; ++j) {
      const int idx = tid + 256*j;
      const int d4 = idx & 15, kk = idx >> 4;
      const float4 vv = *(const float4*)(v_full + ((size_t)b*kN + k0 + kk)*kE + h*kDV + d4*4);
      *(float4*)&v_lds[kk*68 + d4*4] = vv;
    }
    __syncthreads();
    #pragma unroll
    for (int kk = 0; kk < 32; ++kk) {
      const float p = p_lds[q*33 + kk];
      const float4 va = *(const float4*)&v_lds[kk*68 + dg*8];
      const float4 vb = *(const float4*)&v_lds[kk*68 + dg*8 + 4];
      acc[0]+=p*va.x; acc[1]+=p*va.y; acc[2]+=p*va.z; acc[3]+=p*va.w;
      acc[4]+=p*vb.x; acc[5]+=p*vb.y; acc[6]+=p*vb.z; acc[7]+=p*vb.w;
    }
  }

  // LayerNorm over 64 dims (8 threads x 8 values per q row)
  float s = 0.f, s2 = 0.f;
  #pragma unroll
  for (int j = 0; j < 8; ++j) { s += acc[j]; s2 += acc[j]*acc[j]; }
  #pragma unroll
  for (int off = 1; off < 8; off <<= 1) { s += __shfl_xor(s, off); s2 += __shfl_xor(s2, off); }
  const float mu  = s * (1.0f/kDV);
  const float var = s2 * (1.0f/kDV) - mu*mu;
  const float rstd = rsqrtf(var + 1e-5f);
  const float4 w1 = *(const float4*)(ln_w + dg*8);
  const float4 w2 = *(const float4*)(ln_w + dg*8 + 4);
  const float4 b1 = *(const float4*)(ln_b + dg*8);
  const float4 b2 = *(const float4*)(ln_b + dg*8 + 4);
  float4 o1, o2;
  o1.x=(acc[0]-mu)*rstd*w1.x+b1.x; o1.y=(acc[1]-mu)*rstd*w1.y+b1.y;
  o1.z=(acc[2]-mu)*rstd*w1.z+b1.z; o1.w=(acc[3]-mu)*rstd*w1.w+b1.w;
  o2.x=(acc[4]-mu)*rstd*w2.x+b2.x; o2.y=(acc[5]-mu)*rstd*w2.y+b2.y;
  o2.z=(acc[6]-mu)*rstd*w2.z+b2.z; o2.w=(acc[7]-mu)*rstd*w2.w+b2.w;
  float* dst = attn_flat + ((size_t)(b*kN + q0 + q)) * kE + h*kDV + dg*8;
  *(float4*)dst = o1;
  *(float4*)(dst + 4) = o2;
}

// ----------------------------------------------------------------------------
extern "C" void kernel_launch(void* const* d_in, const int* in_sizes, int n_in,
                              void* d_out, int out_size, void* d_ws, size_t ws_size,
                              hipStream_t stream) {
  const float* x     = (const float*)d_in[0];
  const float* u     = (const float*)d_in[1];
  const int*   umask = (const int*)d_in[2];
  const float* v_w   = (const float*)d_in[3];
  const float* out_w = (const float*)d_in[4];
  const float* uw    = (const float*)d_in[5];
  const float* ubias = (const float*)d_in[6];
  const float* lq1   = (const float*)d_in[7];
  const float* lk1   = (const float*)d_in[8];
  const float* lq2   = (const float*)d_in[9];
  const float* lk2   = (const float*)d_in[10];
  const float* ln_w  = (const float*)d_in[11];
  const float* ln_b  = (const float*)d_in[12];
  float* out = (float*)d_out;

  char* ws = (char*)d_ws;
  const size_t off_v  = 256;
  const size_t sz_v   = (size_t)kB*kN*kE*4;           // 4 MB
  const size_t off_ue = off_v + sz_v;
  const size_t sz_ue  = (size_t)kB*kH2*kN*kN*4;       // 67 MB
  const size_t off_at = off_ue + sz_ue;
  if (ws_size < off_at + sz_v) return;                 // need ~75.5 MB
  float* lam     = (float*)(ws);
  float* v_full  = (float*)(ws + off_v);
  float* ue_t    = (float*)(ws + off_ue);
  float* attn_fl = (float*)(ws + off_at);

  hipLaunchKernelGGL(lam_kernel, dim3(1), dim3(64), 0, stream, lq1, lk1, lq2, lk2, lam);
  hipLaunchKernelGGL(sgemm_abt, dim3(kE/64, (kB*kN)/64), dim3(256), 0, stream,
                     x, v_w, v_full, kB*kN, kE, kE);
  hipLaunchKernelGGL(ue_kernel, dim3(kN/32, kN/16, kB), dim3(256), 0, stream,
                     u, umask, uw, ubias, ue_t);
  hipLaunchKernelGGL(attn_kernel, dim3(kN/32, kH, kB), dim3(256), 0, stream,
                     ue_t, v_full, lam, ln_w, ln_b, attn_fl);
  hipLaunchKernelGGL(sgemm_abt, dim3(kE/64, (kB*kN)/64), dim3(256), 0, stream,
                     attn_fl, out_w, out, kB*kN, kE, kE);
}

// Round 2
// 209.840 us; speedup vs baseline: 1.2281x; 1.2281x over previous
//
#include <hip/hip_runtime.h>
#include <math.h>

typedef _Float16 f16x8 __attribute__((ext_vector_type(8)));
typedef float    f32x4 __attribute__((ext_vector_type(4)));

constexpr int kB  = 4;
constexpr int kN  = 512;
constexpr int kE  = 512;
constexpr int kH  = 8;
constexpr int kH2 = 16;
constexpr int kC  = 64;
constexpr int kDV = 64;
constexpr float kLamInit = 0.2f;

// ---------------------------------------------------------------- K0: lambda
__global__ void lam_kernel(const float* __restrict__ lq1, const float* __restrict__ lk1,
                           const float* __restrict__ lq2, const float* __restrict__ lk2,
                           float* __restrict__ lam_out) {
  int lane = threadIdx.x;  // 64 threads
  float s1 = 0.f, s2 = 0.f;
  for (int i = lane; i < kE; i += 64) { s1 += lq1[i] * lk1[i]; s2 += lq2[i] * lk2[i]; }
  #pragma unroll
  for (int off = 32; off; off >>= 1) { s1 += __shfl_xor(s1, off); s2 += __shfl_xor(s2, off); }
  if (lane == 0) lam_out[0] = expf(s1) - expf(s2) + kLamInit;
}

// ------------------------------------------------- K1/K4: C[M,N] = A[M,K] * B[N,K]^T
__global__ __launch_bounds__(256) void sgemm_abt(const float* __restrict__ A,
                                                 const float* __restrict__ B,
                                                 float* __restrict__ C,
                                                 int M, int N, int K) {
  __shared__ float As[16][68];
  __shared__ float Bs[16][68];
  const int tid = threadIdx.x;
  const int tx = tid & 15, ty = tid >> 4;
  const int m0 = blockIdx.y * 64, f0 = blockIdx.x * 64;
  const int lr = tid >> 2, lc = tid & 3;
  float acc[4][4] = {};
  const float* Ap = A + (size_t)(m0 + lr) * K + lc * 4;
  const float* Bp = B + (size_t)(f0 + lr) * K + lc * 4;
  for (int k0 = 0; k0 < K; k0 += 16) {
    const float4 av = *(const float4*)(Ap + k0);
    const float4 bv = *(const float4*)(Bp + k0);
    __syncthreads();
    As[lc*4+0][lr]=av.x; As[lc*4+1][lr]=av.y; As[lc*4+2][lr]=av.z; As[lc*4+3][lr]=av.w;
    Bs[lc*4+0][lr]=bv.x; Bs[lc*4+1][lr]=bv.y; Bs[lc*4+2][lr]=bv.z; Bs[lc*4+3][lr]=bv.w;
    __syncthreads();
    #pragma unroll
    for (int k = 0; k < 16; ++k) {
      const float4 a = *(const float4*)&As[k][ty*4];
      const float4 b = *(const float4*)&Bs[k][tx*4];
      acc[0][0]+=a.x*b.x; acc[0][1]+=a.x*b.y; acc[0][2]+=a.x*b.z; acc[0][3]+=a.x*b.w;
      acc[1][0]+=a.y*b.x; acc[1][1]+=a.y*b.y; acc[1][2]+=a.y*b.z; acc[1][3]+=a.y*b.w;
      acc[2][0]+=a.z*b.x; acc[2][1]+=a.z*b.y; acc[2][2]+=a.z*b.z; acc[2][3]+=a.z*b.w;
      acc[3][0]+=a.w*b.x; acc[3][1]+=a.w*b.y; acc[3][2]+=a.w*b.z; acc[3][3]+=a.w*b.w;
    }
  }
  #pragma unroll
  for (int i = 0; i < 4; ++i) {
    float4 o = make_float4(acc[i][0], acc[i][1], acc[i][2], acc[i][3]);
    *(float4*)(C + (size_t)(m0 + ty*4 + i) * N + f0 + tx*4) = o;
  }
}

// -------------------- K2 (MFMA): ue16[b,h2,q,k] = f16(u @ w^T + bias), mask -> -inf
// Block: 16-q x 32-k tile, 256 thr / 4 waves. u staged f16 in LDS (double-buffered
// 8-k substages, chunk-XOR swizzle so A-frag ds_read_b128 is conflict-free).
// One mfma_f32_16x16x32_f16 per (k, c-half): A = u[16q x 32c], B = w[32c x 16h2].
// C/D layout (measured m89): col = lane&15 (h2), row = (lane>>4)*4 + reg (q).
__global__ __launch_bounds__(256) void ue_mfma_kernel(
    const float* __restrict__ u, const int* __restrict__ umask,
    const float* __restrict__ uw, const float* __restrict__ ub,
    _Float16* __restrict__ ue16) {
  __shared__ _Float16 ust[2][8192];   // [kk 0..7][q 0..15][slot 0..7][8 halves] 16KB each
  __shared__ _Float16 obuf[2048];     // [q' 0..15][h2 0..15][ks 0..7] 4KB
  const int tid = threadIdx.x;
  const int lane = tid & 63;
  const int wv   = tid >> 6;
  const int q0 = blockIdx.x * 16;
  const int k0 = blockIdx.y * 32;
  const int b  = blockIdx.z;
  const int l15 = lane & 15, l4 = lane >> 4;

  // B-fragments: lane holds w[h2 = l15][c = ch*32 + l4*8 + j], j = 0..7
  f16x8 bfrag[2];
  #pragma unroll
  for (int ch = 0; ch < 2; ++ch) {
    const float* wp = uw + l15 * 64 + ch * 32 + l4 * 8;
    const float4 wa = *(const float4*)wp;
    const float4 wb = *(const float4*)(wp + 4);
    f16x8 bf;
    bf[0]=(_Float16)wa.x; bf[1]=(_Float16)wa.y; bf[2]=(_Float16)wa.z; bf[3]=(_Float16)wa.w;
    bf[4]=(_Float16)wb.x; bf[5]=(_Float16)wb.y; bf[6]=(_Float16)wb.z; bf[7]=(_Float16)wb.w;
    bfrag[ch] = bf;
  }
  const float bias = ub[l15];

  float4 rv[8];
  // prologue: stage substage 0
  #pragma unroll
  for (int r = 0; r < 8; ++r) {
    const int i = tid + 256 * r;
    const int c4 = i & 15, q = (i >> 4) & 15, kk = i >> 8;
    rv[r] = *(const float4*)(u + (((size_t)(b * kN + k0 + kk)) * kN + q0 + q) * kC + c4 * 4);
  }
  #pragma unroll
  for (int r = 0; r < 8; ++r) {
    const int i = tid + 256 * r;
    const int c4 = i & 15, q = (i >> 4) & 15, kk = i >> 8;
    const int slot = (c4 >> 1) ^ (q & 7);
    union { _Float16 h[4]; uint2 u2; } P;
    P.h[0]=(_Float16)rv[r].x; P.h[1]=(_Float16)rv[r].y;
    P.h[2]=(_Float16)rv[r].z; P.h[3]=(_Float16)rv[r].w;
    *(uint2*)&ust[0][kk * 1024 + q * 64 + slot * 8 + (c4 & 1) * 4] = P.u2;
  }
  __syncthreads();

  for (int s = 0; s < 4; ++s) {
    const int cur = s & 1;
    if (s < 3) {  // issue next substage's global loads early (hide HBM latency)
      #pragma unroll
      for (int r = 0; r < 8; ++r) {
        const int i = tid + 256 * r;
        const int c4 = i & 15, q = (i >> 4) & 15, kk = i >> 8;
        rv[r] = *(const float4*)(u + (((size_t)(b * kN + k0 + (s+1)*8 + kk)) * kN + q0 + q) * kC + c4 * 4);
      }
    }
    // compute: this wave owns k-slots wv*2 and wv*2+1 of the 8-k substage
    #pragma unroll
    for (int t = 0; t < 2; ++t) {
      const int ksl = wv * 2 + t;  // 0..7
      f32x4 acc = {0.f, 0.f, 0.f, 0.f};
      #pragma unroll
      for (int ch = 0; ch < 2; ++ch) {
        const int slot = ((ch << 2) | l4) ^ (l15 & 7);
        const int4 ra = *(const int4*)&ust[cur][ksl * 1024 + l15 * 64 + slot * 8];
        acc = __builtin_amdgcn_mfma_f32_16x16x32_f16(
                  __builtin_bit_cast(f16x8, ra), bfrag[ch], acc, 0, 0, 0);
      }
      const int kglob = k0 + s * 8 + ksl;
      const int* mrow = umask + (((size_t)(b * kN + kglob)) * kN + q0) * kH2 + l15;
      #pragma unroll
      for (int r = 0; r < 4; ++r) {
        const int qo = l4 * 4 + r;
        const float val = acc[r] + bias;
        const int msk = mrow[qo * kH2];
        obuf[qo * 128 + l15 * 8 + ksl] = msk ? (_Float16)(-INFINITY) : (_Float16)val;
      }
    }
    __syncthreads();
    // flush: thread (q' = tid>>4, h2 = tid&15) stores 8 k-contiguous halves (16B)
    {
      const int qo = tid >> 4, hh = tid & 15;
      const int4 ov = *(const int4*)&obuf[qo * 128 + hh * 8];
      *(int4*)(ue16 + (((size_t)(b * kH2 + hh)) * kN + q0 + qo) * kN + k0 + s * 8) = ov;
    }
    if (s < 3) {
      #pragma unroll
      for (int r = 0; r < 8; ++r) {
        const int i = tid + 256 * r;
        const int c4 = i & 15, q = (i >> 4) & 15, kk = i >> 8;
        const int slot = (c4 >> 1) ^ (q & 7);
        union { _Float16 h[4]; uint2 u2; } P;
        P.h[0]=(_Float16)rv[r].x; P.h[1]=(_Float16)rv[r].y;
        P.h[2]=(_Float16)rv[r].z; P.h[3]=(_Float16)rv[r].w;
        *(uint2*)&ust[cur ^ 1][kk * 1024 + q * 64 + slot * 8 + (c4 & 1) * 4] = P.u2;
      }
    }
    __syncthreads();
  }
}

// ---------- K3: softmax (over k) + diff + PV + LayerNorm, per (b, h, 32-q tile)
__global__ __launch_bounds__(256) void attn_kernel(const _Float16* __restrict__ ue16,
                                                   const float* __restrict__ v_full,
                                                   const float* __restrict__ lam_p,
                                                   const float* __restrict__ ln_w,
                                                   const float* __restrict__ ln_b,
                                                   float* __restrict__ attn_flat) {
  __shared__ float p_lds[32 * 33];
  __shared__ float v_lds[32 * 68];
  __shared__ float m_sh[2][32];
  __shared__ float il_sh[2][32];
  const int tid = threadIdx.x;
  const int qt = blockIdx.x, h = blockIdx.y, b = blockIdx.z;
  const int q0 = qt * 32;
  const float lam = lam_p[0];
  const _Float16* base0 = ue16 + ((size_t)(b * kH2 + 2 * h) * kN) * kN;

  // phase 1: per-row max & sum(exp) for s=0,1 rows (one wave per row)
  const int wave = tid >> 6, lane = tid & 63;
  for (int i = 0; i < 16; ++i) {
    const int r = wave * 16 + i;
    const int s = r >> 5, qloc = r & 31;
    const _Float16* row = base0 + ((size_t)s * kN + q0 + qloc) * kN;
    union { int4 v; _Float16 h[8]; } U;
    U.v = *(const int4*)(row + lane * 8);
    float x0=(float)U.h[0], x1=(float)U.h[1], x2=(float)U.h[2], x3=(float)U.h[3];
    float x4=(float)U.h[4], x5=(float)U.h[5], x6=(float)U.h[6], x7=(float)U.h[7];
    float rm = fmaxf(fmaxf(fmaxf(x0,x1),fmaxf(x2,x3)), fmaxf(fmaxf(x4,x5),fmaxf(x6,x7)));
    #pragma unroll
    for (int off = 32; off; off >>= 1) rm = fmaxf(rm, __shfl_xor(rm, off));
    float e = __expf(x0-rm)+__expf(x1-rm)+__expf(x2-rm)+__expf(x3-rm)
            + __expf(x4-rm)+__expf(x5-rm)+__expf(x6-rm)+__expf(x7-rm);
    #pragma unroll
    for (int off = 32; off; off >>= 1) e += __shfl_xor(e, off);
    if (lane == 0) { m_sh[s][qloc] = rm; il_sh[s][qloc] = 1.0f / e; }
  }
  __syncthreads();

  // phase 2: PV over k tiles of 32
  float acc[8] = {};
  const int q = tid >> 3, dg = tid & 7;
  for (int k0 = 0; k0 < kN; k0 += 32) {
    __syncthreads();
    #pragma unroll
    for (int j = 0; j < 4; ++j) {
      const int idx = tid + 256 * j;
      const int kk = idx & 31, qq = idx >> 5;
      const _Float16* r0 = base0 + (size_t)(q0 + qq) * kN;
      const float e0 = (float)r0[k0 + kk];
      const float e1 = (float)r0[(size_t)kN * kN + k0 + kk];
      p_lds[qq * 33 + kk] = __expf(e0 - m_sh[0][qq]) * il_sh[0][qq]
                          - lam * __expf(e1 - m_sh[1][qq]) * il_sh[1][qq];
    }
    #pragma unroll
    for (int j = 0; j < 2; ++j) {
      const int idx = tid + 256 * j;
      const int d4 = idx & 15, kk = idx >> 4;
      const float4 vv = *(const float4*)(v_full + ((size_t)b * kN + k0 + kk) * kE + h * kDV + d4 * 4);
      *(float4*)&v_lds[kk * 68 + d4 * 4] = vv;
    }
    __syncthreads();
    #pragma unroll
    for (int kk = 0; kk < 32; ++kk) {
      const float p = p_lds[q * 33 + kk];
      const float4 va = *(const float4*)&v_lds[kk * 68 + dg * 8];
      const float4 vb = *(const float4*)&v_lds[kk * 68 + dg * 8 + 4];
      acc[0]+=p*va.x; acc[1]+=p*va.y; acc[2]+=p*va.z; acc[3]+=p*va.w;
      acc[4]+=p*vb.x; acc[5]+=p*vb.y; acc[6]+=p*vb.z; acc[7]+=p*vb.w;
    }
  }

  // LayerNorm over 64 dims (8 threads x 8 values per q row)
  float s = 0.f, s2 = 0.f;
  #pragma unroll
  for (int j = 0; j < 8; ++j) { s += acc[j]; s2 += acc[j] * acc[j]; }
  #pragma unroll
  for (int off = 1; off < 8; off <<= 1) { s += __shfl_xor(s, off); s2 += __shfl_xor(s2, off); }
  const float mu  = s * (1.0f / kDV);
  const float var = s2 * (1.0f / kDV) - mu * mu;
  const float rstd = rsqrtf(var + 1e-5f);
  const float4 w1 = *(const float4*)(ln_w + dg * 8);
  const float4 w2 = *(const float4*)(ln_w + dg * 8 + 4);
  const float4 b1 = *(const float4*)(ln_b + dg * 8);
  const float4 b2 = *(const float4*)(ln_b + dg * 8 + 4);
  float4 o1, o2;
  o1.x=(acc[0]-mu)*rstd*w1.x+b1.x; o1.y=(acc[1]-mu)*rstd*w1.y+b1.y;
  o1.z=(acc[2]-mu)*rstd*w1.z+b1.z; o1.w=(acc[3]-mu)*rstd*w1.w+b1.w;
  o2.x=(acc[4]-mu)*rstd*w2.x+b2.x; o2.y=(acc[5]-mu)*rstd*w2.y+b2.y;
  o2.z=(acc[6]-mu)*rstd*w2.z+b2.z; o2.w=(acc[7]-mu)*rstd*w2.w+b2.w;
  float* dst = attn_flat + ((size_t)(b * kN + q0 + q)) * kE + h * kDV + dg * 8;
  *(float4*)dst = o1;
  *(float4*)(dst + 4) = o2;
}

// ----------------------------------------------------------------------------
extern "C" void kernel_launch(void* const* d_in, const int* in_sizes, int n_in,
                              void* d_out, int out_size, void* d_ws, size_t ws_size,
                              hipStream_t stream) {
  const float* x     = (const float*)d_in[0];
  const float* u     = (const float*)d_in[1];
  const int*   umask = (const int*)d_in[2];
  const float* v_w   = (const float*)d_in[3];
  const float* out_w = (const float*)d_in[4];
  const float* uw    = (const float*)d_in[5];
  const float* ubias = (const float*)d_in[6];
  const float* lq1   = (const float*)d_in[7];
  const float* lk1   = (const float*)d_in[8];
  const float* lq2   = (const float*)d_in[9];
  const float* lk2   = (const float*)d_in[10];
  const float* ln_w  = (const float*)d_in[11];
  const float* ln_b  = (const float*)d_in[12];
  float* out = (float*)d_out;

  char* ws = (char*)d_ws;
  const size_t off_v  = 256;
  const size_t sz_v   = (size_t)kB * kN * kE * 4;        // 4 MB
  const size_t off_ue = off_v + sz_v;
  const size_t sz_ue  = (size_t)kB * kH2 * kN * kN * 2;  // 33.5 MB (fp16)
  const size_t off_at = off_ue + sz_ue;
  if (ws_size < off_at + sz_v) return;                   // need ~42 MB
  float*     lam     = (float*)(ws);
  float*     v_full  = (float*)(ws + off_v);
  _Float16*  ue16    = (_Float16*)(ws + off_ue);
  float*     attn_fl = (float*)(ws + off_at);

  hipLaunchKernelGGL(lam_kernel, dim3(1), dim3(64), 0, stream, lq1, lk1, lq2, lk2, lam);
  hipLaunchKernelGGL(sgemm_abt, dim3(kE/64, (kB*kN)/64), dim3(256), 0, stream,
                     x, v_w, v_full, kB*kN, kE, kE);
  hipLaunchKernelGGL(ue_mfma_kernel, dim3(kN/16, kN/32, kB), dim3(256), 0, stream,
                     u, umask, uw, ubias, ue16);
  hipLaunchKernelGGL(attn_kernel, dim3(kN/32, kH, kB), dim3(256), 0, stream,
                     ue16, v_full, lam, ln_w, ln_b, attn_fl);
  hipLaunchKernelGGL(sgemm_abt, dim3(kE/64, (kB*kN)/64), dim3(256), 0, stream,
                     attn_fl, out_w, out, kB*kN, kE, kE);
}

// Round 3
// 187.730 us; speedup vs baseline: 1.3727x; 1.1178x over previous
//
#include <hip/hip_runtime.h>
#include <math.h>

typedef _Float16 f16x8 __attribute__((ext_vector_type(8)));
typedef float    f32x4 __attribute__((ext_vector_type(4)));

constexpr int kB  = 4;
constexpr int kN  = 512;
constexpr int kE  = 512;
constexpr int kH  = 8;
constexpr int kH2 = 16;
constexpr int kC  = 64;
constexpr int kDV = 64;
constexpr float kLamInit = 0.2f;

// ---------------------------------------------------------------- K0: lambda
__global__ void lam_kernel(const float* __restrict__ lq1, const float* __restrict__ lk1,
                           const float* __restrict__ lq2, const float* __restrict__ lk2,
                           float* __restrict__ lam_out) {
  int lane = threadIdx.x;  // 64 threads
  float s1 = 0.f, s2 = 0.f;
  for (int i = lane; i < kE; i += 64) { s1 += lq1[i] * lk1[i]; s2 += lq2[i] * lk2[i]; }
  #pragma unroll
  for (int off = 32; off; off >>= 1) { s1 += __shfl_xor(s1, off); s2 += __shfl_xor(s2, off); }
  if (lane == 0) lam_out[0] = expf(s1) - expf(s2) + kLamInit;
}

// ---------------------------------------------- weight f32 -> f16 conversion
__global__ __launch_bounds__(256) void cvtw_kernel(const float* __restrict__ a,
                                                   _Float16* __restrict__ o, int n4) {
  const int i = blockIdx.x * 256 + threadIdx.x;
  if (i < n4) {
    const float4 v = ((const float4*)a)[i];
    union { _Float16 h[4]; uint2 u2; } P;
    P.h[0] = (_Float16)v.x; P.h[1] = (_Float16)v.y;
    P.h[2] = (_Float16)v.z; P.h[3] = (_Float16)v.w;
    *(uint2*)(o + i * 4) = P.u2;
  }
}

// --------------------- hgemm: C[M,F] (f32) = A[M,K] (f32, cvt to f16) x W16[F,K]^T
// 64m x 64f tile per block, 4 waves (wave = 16m strip), K-steps of 32.
// Fragment layouts identical to the validated ue_mfma kernel:
//   A: lane&15 = row, (lane>>4)*8 + j = k     B: lane&15 = col, (lane>>4)*8 + j = k
//   D: col = lane&15, row = (lane>>4)*4 + reg
__global__ __launch_bounds__(256) void hgemm_abt(const float* __restrict__ A,
                                                 const _Float16* __restrict__ W16,
                                                 float* __restrict__ C,
                                                 int M, int F, int K) {
  const int tid = threadIdx.x, lane = tid & 63, wv = tid >> 6;
  const int l15 = lane & 15, l4 = lane >> 4;
  const int m0 = blockIdx.y * 64 + wv * 16;
  const int f0 = blockIdx.x * 64;
  f32x4 acc[4] = {{0,0,0,0},{0,0,0,0},{0,0,0,0},{0,0,0,0}};
  const float*     Ap = A   + (size_t)(m0 + l15) * K + l4 * 8;
  const _Float16*  Wp = W16 + (size_t)(f0 + l15) * K + l4 * 8;
  for (int k0 = 0; k0 < K; k0 += 32) {
    const float4 a0 = *(const float4*)(Ap + k0);
    const float4 a1 = *(const float4*)(Ap + k0 + 4);
    f16x8 af;
    af[0]=(_Float16)a0.x; af[1]=(_Float16)a0.y; af[2]=(_Float16)a0.z; af[3]=(_Float16)a0.w;
    af[4]=(_Float16)a1.x; af[5]=(_Float16)a1.y; af[6]=(_Float16)a1.z; af[7]=(_Float16)a1.w;
    #pragma unroll
    for (int t = 0; t < 4; ++t) {
      const f16x8 bf = *(const f16x8*)(Wp + (size_t)t * 16 * K + k0);
      acc[t] = __builtin_amdgcn_mfma_f32_16x16x32_f16(af, bf, acc[t], 0, 0, 0);
    }
  }
  #pragma unroll
  for (int t = 0; t < 4; ++t)
    #pragma unroll
    for (int r = 0; r < 4; ++r)
      C[(size_t)(m0 + l4 * 4 + r) * F + f0 + t * 16 + l15] = acc[t][r];
}

// -------------------- K2 (MFMA, LDS-free): ue16[b,h2,q,k] = f16(u @ w^T + b), mask -> -inf
// Grid (32 qt, 16 kt, b); 4 waves; wave owns 16q x 8k strip. Per k: A-frag = u rows
// loaded directly (32B contiguous per lane), 2 mfma (c-halves); D gives lane 4 q-rows
// for one h2 col. After 8 k's each lane packs 8 k-values -> one 16B store per (q,h2).
__global__ __launch_bounds__(256) void ue_mfma2_kernel(
    const float* __restrict__ u, const int* __restrict__ umask,
    const float* __restrict__ uw, const float* __restrict__ ub,
    _Float16* __restrict__ ue16) {
  const int tid = threadIdx.x, lane = tid & 63, wv = tid >> 6;
  const int l15 = lane & 15, l4 = lane >> 4;
  const int q0    = blockIdx.x * 16;
  const int kbase = blockIdx.y * 32 + wv * 8;
  const int b     = blockIdx.z;

  // B-fragments: lane holds w[h2=l15][c = ch*32 + l4*8 + j]
  f16x8 bfrag[2];
  #pragma unroll
  for (int ch = 0; ch < 2; ++ch) {
    const float* wp = uw + l15 * 64 + ch * 32 + l4 * 8;
    const float4 wa = *(const float4*)wp;
    const float4 wb = *(const float4*)(wp + 4);
    f16x8 bf;
    bf[0]=(_Float16)wa.x; bf[1]=(_Float16)wa.y; bf[2]=(_Float16)wa.z; bf[3]=(_Float16)wa.w;
    bf[4]=(_Float16)wb.x; bf[5]=(_Float16)wb.y; bf[6]=(_Float16)wb.z; bf[7]=(_Float16)wb.w;
    bfrag[ch] = bf;
  }
  const float bias = ub[l15];

  float vals[4][8];
  #pragma unroll
  for (int kk = 0; kk < 8; ++kk) {
    const int k = kbase + kk;
    const float* up = u + (((size_t)(b * kN + k)) * kN + q0 + l15) * kC + l4 * 8;
    f32x4 acc = {0.f, 0.f, 0.f, 0.f};
    #pragma unroll
    for (int ch = 0; ch < 2; ++ch) {
      const float4 a0 = *(const float4*)(up + ch * 32);
      const float4 a1 = *(const float4*)(up + ch * 32 + 4);
      f16x8 af;
      af[0]=(_Float16)a0.x; af[1]=(_Float16)a0.y; af[2]=(_Float16)a0.z; af[3]=(_Float16)a0.w;
      af[4]=(_Float16)a1.x; af[5]=(_Float16)a1.y; af[6]=(_Float16)a1.z; af[7]=(_Float16)a1.w;
      acc = __builtin_amdgcn_mfma_f32_16x16x32_f16(af, bfrag[ch], acc, 0, 0, 0);
    }
    const int* mrow = umask + (((size_t)(b * kN + k)) * kN + q0) * kH2 + l15;
    #pragma unroll
    for (int r = 0; r < 4; ++r) {
      const float v = acc[r] + bias;
      vals[r][kk] = mrow[(l4 * 4 + r) * kH2] ? -INFINITY : v;
    }
  }
  #pragma unroll
  for (int r = 0; r < 4; ++r) {
    union { _Float16 h[8]; int4 v; } P;
    #pragma unroll
    for (int kk = 0; kk < 8; ++kk) P.h[kk] = (_Float16)vals[r][kk];
    *(int4*)(ue16 + (((size_t)(b * kH2 + l15)) * kN + q0 + l4 * 4 + r) * kN + kbase) = P.v;
  }
}

// ---------- K3: softmax (over k) + diff + PV + LayerNorm, per (b, h, 32-q tile)
__global__ __launch_bounds__(256) void attn_kernel(const _Float16* __restrict__ ue16,
                                                   const float* __restrict__ v_full,
                                                   const float* __restrict__ lam_p,
                                                   const float* __restrict__ ln_w,
                                                   const float* __restrict__ ln_b,
                                                   float* __restrict__ attn_flat) {
  __shared__ float p_lds[32 * 33];
  __shared__ float v_lds[32 * 68];
  __shared__ float m_sh[2][32];
  __shared__ float il_sh[2][32];
  const int tid = threadIdx.x;
  const int qt = blockIdx.x, h = blockIdx.y, b = blockIdx.z;
  const int q0 = qt * 32;
  const float lam = lam_p[0];
  const _Float16* base0 = ue16 + ((size_t)(b * kH2 + 2 * h) * kN) * kN;

  // phase 1: per-row max & sum(exp) for s=0,1 rows (one wave per row)
  const int wave = tid >> 6, lane = tid & 63;
  for (int i = 0; i < 16; ++i) {
    const int r = wave * 16 + i;
    const int s = r >> 5, qloc = r & 31;
    const _Float16* row = base0 + ((size_t)s * kN + q0 + qloc) * kN;
    union { int4 v; _Float16 h[8]; } U;
    U.v = *(const int4*)(row + lane * 8);
    float x0=(float)U.h[0], x1=(float)U.h[1], x2=(float)U.h[2], x3=(float)U.h[3];
    float x4=(float)U.h[4], x5=(float)U.h[5], x6=(float)U.h[6], x7=(float)U.h[7];
    float rm = fmaxf(fmaxf(fmaxf(x0,x1),fmaxf(x2,x3)), fmaxf(fmaxf(x4,x5),fmaxf(x6,x7)));
    #pragma unroll
    for (int off = 32; off; off >>= 1) rm = fmaxf(rm, __shfl_xor(rm, off));
    float e = __expf(x0-rm)+__expf(x1-rm)+__expf(x2-rm)+__expf(x3-rm)
            + __expf(x4-rm)+__expf(x5-rm)+__expf(x6-rm)+__expf(x7-rm);
    #pragma unroll
    for (int off = 32; off; off >>= 1) e += __shfl_xor(e, off);
    if (lane == 0) { m_sh[s][qloc] = rm; il_sh[s][qloc] = 1.0f / e; }
  }
  __syncthreads();

  // phase 2: PV over k tiles of 32
  float acc[8] = {};
  const int q = tid >> 3, dg = tid & 7;
  for (int k0 = 0; k0 < kN; k0 += 32) {
    __syncthreads();
    #pragma unroll
    for (int j = 0; j < 4; ++j) {
      const int idx = tid + 256 * j;
      const int kk = idx & 31, qq = idx >> 5;
      const _Float16* r0 = base0 + (size_t)(q0 + qq) * kN;
      const float e0 = (float)r0[k0 + kk];
      const float e1 = (float)r0[(size_t)kN * kN + k0 + kk];
      p_lds[qq * 33 + kk] = __expf(e0 - m_sh[0][qq]) * il_sh[0][qq]
                          - lam * __expf(e1 - m_sh[1][qq]) * il_sh[1][qq];
    }
    #pragma unroll
    for (int j = 0; j < 2; ++j) {
      const int idx = tid + 256 * j;
      const int d4 = idx & 15, kk = idx >> 4;
      const float4 vv = *(const float4*)(v_full + ((size_t)b * kN + k0 + kk) * kE + h * kDV + d4 * 4);
      *(float4*)&v_lds[kk * 68 + d4 * 4] = vv;
    }
    __syncthreads();
    #pragma unroll
    for (int kk = 0; kk < 32; ++kk) {
      const float p = p_lds[q * 33 + kk];
      const float4 va = *(const float4*)&v_lds[kk * 68 + dg * 8];
      const float4 vb = *(const float4*)&v_lds[kk * 68 + dg * 8 + 4];
      acc[0]+=p*va.x; acc[1]+=p*va.y; acc[2]+=p*va.z; acc[3]+=p*va.w;
      acc[4]+=p*vb.x; acc[5]+=p*vb.y; acc[6]+=p*vb.z; acc[7]+=p*vb.w;
    }
  }

  // LayerNorm over 64 dims (8 threads x 8 values per q row)
  float s = 0.f, s2 = 0.f;
  #pragma unroll
  for (int j = 0; j < 8; ++j) { s += acc[j]; s2 += acc[j] * acc[j]; }
  #pragma unroll
  for (int off = 1; off < 8; off <<= 1) { s += __shfl_xor(s, off); s2 += __shfl_xor(s2, off); }
  const float mu  = s * (1.0f / kDV);
  const float var = s2 * (1.0f / kDV) - mu * mu;
  const float rstd = rsqrtf(var + 1e-5f);
  const float4 w1 = *(const float4*)(ln_w + dg * 8);
  const float4 w2 = *(const float4*)(ln_w + dg * 8 + 4);
  const float4 b1 = *(const float4*)(ln_b + dg * 8);
  const float4 b2 = *(const float4*)(ln_b + dg * 8 + 4);
  float4 o1, o2;
  o1.x=(acc[0]-mu)*rstd*w1.x+b1.x; o1.y=(acc[1]-mu)*rstd*w1.y+b1.y;
  o1.z=(acc[2]-mu)*rstd*w1.z+b1.z; o1.w=(acc[3]-mu)*rstd*w1.w+b1.w;
  o2.x=(acc[4]-mu)*rstd*w2.x+b2.x; o2.y=(acc[5]-mu)*rstd*w2.y+b2.y;
  o2.z=(acc[6]-mu)*rstd*w2.z+b2.z; o2.w=(acc[7]-mu)*rstd*w2.w+b2.w;
  float* dst = attn_flat + ((size_t)(b * kN + q0 + q)) * kE + h * kDV + dg * 8;
  *(float4*)dst = o1;
  *(float4*)(dst + 4) = o2;
}

// ----------------------------------------------------------------------------
extern "C" void kernel_launch(void* const* d_in, const int* in_sizes, int n_in,
                              void* d_out, int out_size, void* d_ws, size_t ws_size,
                              hipStream_t stream) {
  const float* x     = (const float*)d_in[0];
  const float* u     = (const float*)d_in[1];
  const int*   umask = (const int*)d_in[2];
  const float* v_w   = (const float*)d_in[3];
  const float* out_w = (const float*)d_in[4];
  const float* uw    = (const float*)d_in[5];
  const float* ubias = (const float*)d_in[6];
  const float* lq1   = (const float*)d_in[7];
  const float* lk1   = (const float*)d_in[8];
  const float* lq2   = (const float*)d_in[9];
  const float* lk2   = (const float*)d_in[10];
  const float* ln_w  = (const float*)d_in[11];
  const float* ln_b  = (const float*)d_in[12];
  float* out = (float*)d_out;

  char* ws = (char*)d_ws;
  const size_t off_v   = 256;
  const size_t sz_v    = (size_t)kB * kN * kE * 4;        // 4 MB
  const size_t off_ue  = off_v + sz_v;
  const size_t sz_ue   = (size_t)kB * kH2 * kN * kN * 2;  // 33.5 MB (f16)
  const size_t off_at  = off_ue + sz_ue;
  const size_t off_w1  = off_at + sz_v;
  const size_t sz_w16  = (size_t)kE * kE * 2;             // 512 KB
  const size_t off_w2  = off_w1 + sz_w16;
  if (ws_size < off_w2 + sz_w16) return;                  // ~43.5 MB
  float*     lam     = (float*)(ws);
  float*     v_full  = (float*)(ws + off_v);
  _Float16*  ue16    = (_Float16*)(ws + off_ue);
  float*     attn_fl = (float*)(ws + off_at);
  _Float16*  w16v    = (_Float16*)(ws + off_w1);
  _Float16*  w16o    = (_Float16*)(ws + off_w2);

  hipLaunchKernelGGL(lam_kernel, dim3(1), dim3(64), 0, stream, lq1, lk1, lq2, lk2, lam);
  hipLaunchKernelGGL(cvtw_kernel, dim3(kE * kE / 4 / 256), dim3(256), 0, stream,
                     v_w, w16v, kE * kE / 4);
  hipLaunchKernelGGL(cvtw_kernel, dim3(kE * kE / 4 / 256), dim3(256), 0, stream,
                     out_w, w16o, kE * kE / 4);
  hipLaunchKernelGGL(hgemm_abt, dim3(kE / 64, (kB * kN) / 64), dim3(256), 0, stream,
                     x, w16v, v_full, kB * kN, kE, kE);
  hipLaunchKernelGGL(ue_mfma2_kernel, dim3(kN / 16, kN / 32, kB), dim3(256), 0, stream,
                     u, umask, uw, ubias, ue16);
  hipLaunchKernelGGL(attn_kernel, dim3(kN / 32, kH, kB), dim3(256), 0, stream,
                     ue16, v_full, lam, ln_w, ln_b, attn_fl);
  hipLaunchKernelGGL(hgemm_abt, dim3(kE / 64, (kB * kN) / 64), dim3(256), 0, stream,
                     attn_fl, w16o, out, kB * kN, kE, kE);
}

// Round 4
// 150.587 us; speedup vs baseline: 1.7113x; 1.2467x over previous
//
#include <hip/hip_runtime.h>
#include <math.h>

typedef _Float16 f16x8 __attribute__((ext_vector_type(8)));
typedef float    f32x4 __attribute__((ext_vector_type(4)));

constexpr int kB  = 4;
constexpr int kN  = 512;
constexpr int kE  = 512;
constexpr int kH  = 8;
constexpr int kH2 = 16;
constexpr int kC  = 64;
constexpr int kDV = 64;
constexpr float kLamInit = 0.2f;

// ---- prep: f32->f16 for x, v_w, out_w; block 1536 computes lambda ----------
__global__ __launch_bounds__(256) void prep_kernel(
    const float* __restrict__ x, const float* __restrict__ vw,
    const float* __restrict__ ow,
    const float* __restrict__ lq1, const float* __restrict__ lk1,
    const float* __restrict__ lq2, const float* __restrict__ lk2,
    _Float16* __restrict__ x16, _Float16* __restrict__ w16v,
    _Float16* __restrict__ w16o, float* __restrict__ lam_out) {
  const int bid = blockIdx.x;
  if (bid < 1536) {
    const float* src; _Float16* dst; int base;
    if (bid < 1024)      { src = x;  dst = x16;  base = bid; }
    else if (bid < 1280) { src = vw; dst = w16v; base = bid - 1024; }
    else                 { src = ow; dst = w16o; base = bid - 1280; }
    const int i = base * 256 + threadIdx.x;
    const float4 v = ((const float4*)src)[i];
    union { _Float16 h[4]; uint2 u2; } P;
    P.h[0]=(_Float16)v.x; P.h[1]=(_Float16)v.y;
    P.h[2]=(_Float16)v.z; P.h[3]=(_Float16)v.w;
    *(uint2*)(dst + i * 4) = P.u2;
  } else if (threadIdx.x < 64) {
    float s1 = 0.f, s2 = 0.f;
    for (int i = threadIdx.x; i < kE; i += 64) { s1 += lq1[i]*lk1[i]; s2 += lq2[i]*lk2[i]; }
    #pragma unroll
    for (int o = 32; o; o >>= 1) { s1 += __shfl_xor(s1, o); s2 += __shfl_xor(s2, o); }
    if (threadIdx.x == 0) lam_out[0] = expf(s1) - expf(s2) + kLamInit;
  }
}

// ---- hgemm: C[M,F] = A16[M,K] x W16[F,K]^T, C is f16 or f32 ---------------
// A-frag: lane&15 = row, (lane>>4)*8+j = k; B same; D: col=lane&15, row=(lane>>4)*4+r.
template<typename CT>
__global__ __launch_bounds__(256) void hgemm16(const _Float16* __restrict__ A16,
                                               const _Float16* __restrict__ W16,
                                               CT* __restrict__ C,
                                               int M, int F, int K) {
  const int tid = threadIdx.x, lane = tid & 63, wv = tid >> 6;
  const int l15 = lane & 15, l4 = lane >> 4;
  const int m0 = blockIdx.y * 64 + wv * 16;
  const int f0 = blockIdx.x * 64;
  f32x4 acc[4] = {{0,0,0,0},{0,0,0,0},{0,0,0,0},{0,0,0,0}};
  const _Float16* Ap = A16 + (size_t)(m0 + l15) * K + l4 * 8;
  const _Float16* Wp = W16 + (size_t)(f0 + l15) * K + l4 * 8;
  for (int k0 = 0; k0 < K; k0 += 32) {
    const f16x8 af = *(const f16x8*)(Ap + k0);
    #pragma unroll
    for (int t = 0; t < 4; ++t) {
      const f16x8 bf = *(const f16x8*)(Wp + (size_t)t * 16 * K + k0);
      acc[t] = __builtin_amdgcn_mfma_f32_16x16x32_f16(af, bf, acc[t], 0, 0, 0);
    }
  }
  #pragma unroll
  for (int t = 0; t < 4; ++t)
    #pragma unroll
    for (int r = 0; r < 4; ++r)
      C[(size_t)(m0 + l4 * 4 + r) * F + f0 + t * 16 + l15] = (CT)acc[t][r];
}

// ---- K2 (unchanged, validated): ue16[b,h2,q,k] = f16(u @ w^T + b), mask->-inf
__global__ __launch_bounds__(256) void ue_mfma2_kernel(
    const float* __restrict__ u, const int* __restrict__ umask,
    const float* __restrict__ uw, const float* __restrict__ ub,
    _Float16* __restrict__ ue16) {
  const int tid = threadIdx.x, lane = tid & 63, wv = tid >> 6;
  const int l15 = lane & 15, l4 = lane >> 4;
  const int q0    = blockIdx.x * 16;
  const int kbase = blockIdx.y * 32 + wv * 8;
  const int b     = blockIdx.z;
  f16x8 bfrag[2];
  #pragma unroll
  for (int ch = 0; ch < 2; ++ch) {
    const float* wp = uw + l15 * 64 + ch * 32 + l4 * 8;
    const float4 wa = *(const float4*)wp;
    const float4 wb = *(const float4*)(wp + 4);
    f16x8 bf;
    bf[0]=(_Float16)wa.x; bf[1]=(_Float16)wa.y; bf[2]=(_Float16)wa.z; bf[3]=(_Float16)wa.w;
    bf[4]=(_Float16)wb.x; bf[5]=(_Float16)wb.y; bf[6]=(_Float16)wb.z; bf[7]=(_Float16)wb.w;
    bfrag[ch] = bf;
  }
  const float bias = ub[l15];
  float vals[4][8];
  #pragma unroll
  for (int kk = 0; kk < 8; ++kk) {
    const int k = kbase + kk;
    const float* up = u + (((size_t)(b * kN + k)) * kN + q0 + l15) * kC + l4 * 8;
    f32x4 acc = {0.f, 0.f, 0.f, 0.f};
    #pragma unroll
    for (int ch = 0; ch < 2; ++ch) {
      const float4 a0 = *(const float4*)(up + ch * 32);
      const float4 a1 = *(const float4*)(up + ch * 32 + 4);
      f16x8 af;
      af[0]=(_Float16)a0.x; af[1]=(_Float16)a0.y; af[2]=(_Float16)a0.z; af[3]=(_Float16)a0.w;
      af[4]=(_Float16)a1.x; af[5]=(_Float16)a1.y; af[6]=(_Float16)a1.z; af[7]=(_Float16)a1.w;
      acc = __builtin_amdgcn_mfma_f32_16x16x32_f16(af, bfrag[ch], acc, 0, 0, 0);
    }
    const int* mrow = umask + (((size_t)(b * kN + k)) * kN + q0) * kH2 + l15;
    #pragma unroll
    for (int r = 0; r < 4; ++r) {
      const float v = acc[r] + bias;
      vals[r][kk] = mrow[(l4 * 4 + r) * kH2] ? -INFINITY : v;
    }
  }
  #pragma unroll
  for (int r = 0; r < 4; ++r) {
    union { _Float16 h[8]; int4 v; } P;
    #pragma unroll
    for (int kk = 0; kk < 8; ++kk) P.h[kk] = (_Float16)vals[r][kk];
    *(int4*)(ue16 + (((size_t)(b * kH2 + l15)) * kN + q0 + l4 * 4 + r) * kN + kbase) = P.v;
  }
}

// ---- attn2: one-pass no-max softmax + diff + PV + LN; per (b, h, 32-q tile) -
// Load ue16 once -> exp -> E tiles in LDS + row sums. Then k-tiles: p as f32
// (b128 x 4q), V staged f32; thread = (ks, qg, dg) owns 4q x 8d over 128 k's.
__global__ __launch_bounds__(256) void attn2_kernel(
    const _Float16* __restrict__ ue16, const _Float16* __restrict__ v16,
    const float* __restrict__ lam_p, const float* __restrict__ ln_w,
    const float* __restrict__ ln_b, _Float16* __restrict__ attn16) {
  __shared__ _Float16 E[2][32][512];   // 64 KB exp(ue)
  __shared__ float vs[32][68];         // V tile; reused as combine buffer
  __shared__ float ps[32][36];         // p tile [kk][q]
  __shared__ float stat[2][32];
  __shared__ float istat[2][32];
  const int tid = threadIdx.x;
  const int qt = blockIdx.x, h = blockIdx.y, b = blockIdx.z;
  const int q0 = qt * 32;

  // load + exp + row-sum (4 threads per row, 16 chunks of 8 each)
  {
    const int row = tid >> 2, c0 = tid & 3;
    const int s = row >> 5, q = row & 31;
    const _Float16* src = ue16 + (((size_t)(b * kH2 + 2 * h + s)) * kN + q0 + q) * kN;
    float sum = 0.f;
    #pragma unroll
    for (int i = 0; i < 16; ++i) {
      const int c = c0 + 4 * i;
      union { int4 v; _Float16 hh[8]; } U;
      U.v = *(const int4*)(src + c * 8);
      float e[8];
      #pragma unroll
      for (int j = 0; j < 8; ++j) { e[j] = __expf((float)U.hh[j]); sum += e[j]; }
      union { _Float16 hh[8]; int4 v; } P;
      #pragma unroll
      for (int j = 0; j < 8; ++j) P.hh[j] = (_Float16)e[j];
      *(int4*)&E[s][q][c * 8] = P.v;
    }
    sum += __shfl_xor(sum, 1); sum += __shfl_xor(sum, 2);
    if (c0 == 0) stat[s][q] = sum;
  }
  __syncthreads();
  if (tid < 64) {
    const int s = tid >> 5, q = tid & 31;
    istat[s][q] = (s ? lam_p[0] : 1.0f) / stat[s][q];
  }

  const int ks = tid >> 6, qg = (tid >> 3) & 7, dg = tid & 7;
  float pacc[4][8] = {};
  for (int t0 = 0; t0 < 16; ++t0) {
    const int k0 = t0 * 32;
    __syncthreads();
    {  // stage V tile (f16 global -> f32 LDS)
      const int kk = tid >> 3, d8 = tid & 7;
      union { int4 v; _Float16 hh[8]; } U;
      U.v = *(const int4*)(v16 + ((size_t)(b * kN) + k0 + kk) * kE + h * kDV + d8 * 8);
      #pragma unroll
      for (int j = 0; j < 8; ++j) vs[kk][d8 * 8 + j] = (float)U.hh[j];
    }
    {  // p tile: thread computes 4 (q, kk)
      const int kk = tid & 31, qb = tid >> 5;
      #pragma unroll
      for (int j = 0; j < 4; ++j) {
        const int q = qb + 8 * j;
        const float e0 = (float)E[0][q][k0 + kk];
        const float e1 = (float)E[1][q][k0 + kk];
        ps[kk][q] = e0 * istat[0][q] - e1 * istat[1][q];
      }
    }
    __syncthreads();
    #pragma unroll
    for (int t = 0; t < 8; ++t) {
      const int kk = ks * 8 + t;
      const f32x4 p4 = *(const f32x4*)&ps[kk][qg * 4];
      const f32x4 va = *(const f32x4*)&vs[kk][dg * 8];
      const f32x4 vb = *(const f32x4*)&vs[kk][dg * 8 + 4];
      #pragma unroll
      for (int j = 0; j < 4; ++j) {
        pacc[j][0] += p4[j]*va[0]; pacc[j][1] += p4[j]*va[1];
        pacc[j][2] += p4[j]*va[2]; pacc[j][3] += p4[j]*va[3];
        pacc[j][4] += p4[j]*vb[0]; pacc[j][5] += p4[j]*vb[1];
        pacc[j][6] += p4[j]*vb[2]; pacc[j][7] += p4[j]*vb[3];
      }
    }
  }

  // combine partial accs across the 4 k-split waves into vs
  __syncthreads();
  if (ks == 0) {
    #pragma unroll
    for (int j = 0; j < 4; ++j)
      #pragma unroll
      for (int d = 0; d < 8; ++d) vs[qg * 4 + j][dg * 8 + d] = pacc[j][d];
  }
  #pragma unroll
  for (int w = 1; w < 4; ++w) {
    __syncthreads();
    if (ks == w) {
      #pragma unroll
      for (int j = 0; j < 4; ++j)
        #pragma unroll
        for (int d = 0; d < 8; ++d) vs[qg * 4 + j][dg * 8 + d] += pacc[j][d];
    }
  }
  __syncthreads();

  // LayerNorm over 64 dims (8 threads per q), write f16
  {
    const int q = tid >> 3, d8 = tid & 7;
    float a[8];
    #pragma unroll
    for (int d = 0; d < 8; ++d) a[d] = vs[q][d8 * 8 + d];
    float s = 0.f, s2 = 0.f;
    #pragma unroll
    for (int d = 0; d < 8; ++d) { s += a[d]; s2 += a[d] * a[d]; }
    #pragma unroll
    for (int o = 1; o < 8; o <<= 1) { s += __shfl_xor(s, o); s2 += __shfl_xor(s2, o); }
    const float mu = s * (1.0f / kDV);
    const float var = s2 * (1.0f / kDV) - mu * mu;
    const float rstd = rsqrtf(var + 1e-5f);
    union { _Float16 hh[8]; int4 v; } P;
    #pragma unroll
    for (int d = 0; d < 8; ++d) {
      P.hh[d] = (_Float16)((a[d] - mu) * rstd * ln_w[d8 * 8 + d] + ln_b[d8 * 8 + d]);
    }
    *(int4*)(attn16 + ((size_t)(b * kN + q0 + q)) * kE + h * kDV + d8 * 8) = P.v;
  }
}

// ----------------------------------------------------------------------------
extern "C" void kernel_launch(void* const* d_in, const int* in_sizes, int n_in,
                              void* d_out, int out_size, void* d_ws, size_t ws_size,
                              hipStream_t stream) {
  const float* x     = (const float*)d_in[0];
  const float* u     = (const float*)d_in[1];
  const int*   umask = (const int*)d_in[2];
  const float* v_w   = (const float*)d_in[3];
  const float* out_w = (const float*)d_in[4];
  const float* uw    = (const float*)d_in[5];
  const float* ubias = (const float*)d_in[6];
  const float* lq1   = (const float*)d_in[7];
  const float* lk1   = (const float*)d_in[8];
  const float* lq2   = (const float*)d_in[9];
  const float* lk2   = (const float*)d_in[10];
  const float* ln_w  = (const float*)d_in[11];
  const float* ln_b  = (const float*)d_in[12];
  float* out = (float*)d_out;

  char* ws = (char*)d_ws;
  const size_t sz_half = (size_t)kB * kN * kE * 2;        // 2 MB
  const size_t sz_ue   = (size_t)kB * kH2 * kN * kN * 2;  // 33.5 MB
  const size_t sz_w16  = (size_t)kE * kE * 2;             // 512 KB
  const size_t off_v16 = 256;
  const size_t off_ue  = off_v16 + sz_half;
  const size_t off_a16 = off_ue + sz_ue;
  const size_t off_x16 = off_a16 + sz_half;
  const size_t off_wv  = off_x16 + sz_half;
  const size_t off_wo  = off_wv + sz_w16;
  if (ws_size < off_wo + sz_w16) return;                  // ~41 MB
  float*    lam    = (float*)(ws);
  _Float16* v16    = (_Float16*)(ws + off_v16);
  _Float16* ue16   = (_Float16*)(ws + off_ue);
  _Float16* a16    = (_Float16*)(ws + off_a16);
  _Float16* x16    = (_Float16*)(ws + off_x16);
  _Float16* w16v   = (_Float16*)(ws + off_wv);
  _Float16* w16o   = (_Float16*)(ws + off_wo);

  prep_kernel<<<dim3(1537), dim3(256), 0, stream>>>(
      x, v_w, out_w, lq1, lk1, lq2, lk2, x16, w16v, w16o, lam);
  hgemm16<_Float16><<<dim3(kE / 64, (kB * kN) / 64), dim3(256), 0, stream>>>(
      x16, w16v, v16, kB * kN, kE, kE);
  ue_mfma2_kernel<<<dim3(kN / 16, kN / 32, kB), dim3(256), 0, stream>>>(
      u, umask, uw, ubias, ue16);
  attn2_kernel<<<dim3(kN / 32, kH, kB), dim3(256), 0, stream>>>(
      ue16, v16, lam, ln_w, ln_b, a16);
  hgemm16<float><<<dim3(kE / 64, (kB * kN) / 64), dim3(256), 0, stream>>>(
      a16, w16o, out, kB * kN, kE, kE);
}